// Round 2
// baseline (244.938 us; speedup 1.0000x reference)
//
#include <hip/hip_runtime.h>
#include <math.h>

#define NE 8
#define EPS_F32 1.1920929e-07f

__device__ __forceinline__ void fma8(float xs, const float4& lo, const float4& hi, float* a) {
    a[0] = fmaf(xs, lo.x, a[0]);
    a[1] = fmaf(xs, lo.y, a[1]);
    a[2] = fmaf(xs, lo.z, a[2]);
    a[3] = fmaf(xs, lo.w, a[3]);
    a[4] = fmaf(xs, hi.x, a[4]);
    a[5] = fmaf(xs, hi.y, a[5]);
    a[6] = fmaf(xs, hi.z, a[6]);
    a[7] = fmaf(xs, hi.w, a[7]);
}

// Block = 256 threads = 4 waves, handles 8 tokens.
// wave = pair*2 + ks:  pair selects tokens [pair*4, pair*4+4), ks selects K-half
// (2048 of model_dim each; ks==1 also covers the 64 prompt dims).
// Grid = tokens/8 = 1024 blocks -> 4 blocks/CU -> 16 waves/CU.
__global__ __launch_bounds__(256, 4)
void topk_gate(const float* __restrict__ x,
               const float* __restrict__ prompt,
               const float* __restrict__ W,
               const float* __restrict__ b,
               float* __restrict__ out,
               int tokens)
{
    const int tid  = threadIdx.x;
    const int lane = tid & 63;
    const int wave = tid >> 6;
    const int pair = wave >> 1;     // which 4-token group
    const int ks   = wave & 1;      // which K-half
    const int tblock = blockIdx.x * 8;
    const int tbase  = tblock + pair * 4;

    __shared__ float lds[2][2][4][NE];   // [pair][ks][token][expert]

    float acc[4][NE];
#pragma unroll
    for (int t = 0; t < 4; ++t)
#pragma unroll
        for (int e = 0; e < NE; ++e) acc[t][e] = 0.f;

    const int kofs = ks * 2048;

    // 2048 floats per wave / (64 lanes * 4) = 8 iterations
#pragma unroll 2
    for (int i = 0; i < 8; ++i) {
        const int k = kofs + i * 256 + lane * 4;

        // Issue ALL loads before any FMA so they overlap in flight.
        float4 xv[4];
#pragma unroll
        for (int t = 0; t < 4; ++t)
            xv[t] = *(const float4*)(x + (size_t)(tbase + t) * 4096 + k);

        float4 wlo[4], whi[4];
#pragma unroll
        for (int j = 0; j < 4; ++j) {
            wlo[j] = *(const float4*)(W + (size_t)(k + j) * 8);
            whi[j] = *(const float4*)(W + (size_t)(k + j) * 8 + 4);
        }

#pragma unroll
        for (int t = 0; t < 4; ++t) {
            fma8(xv[t].x, wlo[0], whi[0], acc[t]);
            fma8(xv[t].y, wlo[1], whi[1], acc[t]);
            fma8(xv[t].z, wlo[2], whi[2], acc[t]);
            fma8(xv[t].w, wlo[3], whi[3], acc[t]);
        }
    }

    // prompt part (64 dims): handled by the ks==1 wave, lanes 0..15
    if (ks == 1 && lane < 16) {
        const int k = lane * 4;
        float4 pv[4];
#pragma unroll
        for (int t = 0; t < 4; ++t)
            pv[t] = *(const float4*)(prompt + (size_t)(tbase + t) * 64 + k);
        float4 wlo[4], whi[4];
#pragma unroll
        for (int j = 0; j < 4; ++j) {
            wlo[j] = *(const float4*)(W + (size_t)(4096 + k + j) * 8);
            whi[j] = *(const float4*)(W + (size_t)(4096 + k + j) * 8 + 4);
        }
#pragma unroll
        for (int t = 0; t < 4; ++t) {
            fma8(pv[t].x, wlo[0], whi[0], acc[t]);
            fma8(pv[t].y, wlo[1], whi[1], acc[t]);
            fma8(pv[t].z, wlo[2], whi[2], acc[t]);
            fma8(pv[t].w, wlo[3], whi[3], acc[t]);
        }
    }

    // intra-wave butterfly: every lane gets the wave's full partial logits
#pragma unroll
    for (int t = 0; t < 4; ++t)
#pragma unroll
        for (int e = 0; e < NE; ++e) {
            float v = acc[t][e];
#pragma unroll
            for (int off = 32; off >= 1; off >>= 1)
                v += __shfl_xor(v, off, 64);
            acc[t][e] = v;
        }

    // stash partials: lanes 0..31, lane = t*8 + e
    if (lane < 32) {
        const int t = lane >> 3;
        const int e = lane & 7;
        lds[pair][ks][t][e] = acc[t][e];
    }
    __syncthreads();

    // ---- epilogue: 128 threads, one mask element each ----
    if (tid < 128) {
        const int tl = tid >> 4;          // block-local token 0..7
        const int kk = (tid >> 3) & 1;
        const int ee = tid & 7;
        const int p  = tl >> 2;
        const int t4 = tl & 3;

        float lg[NE];
#pragma unroll
        for (int e = 0; e < NE; ++e)
            lg[e] = lds[p][0][t4][e] + lds[p][1][t4][e] + b[e];

        // top-2, strict > so smallest index wins ties (jax.lax.top_k semantics)
        float v0 = lg[0]; int i0 = 0;
#pragma unroll
        for (int e = 1; e < NE; ++e)
            if (lg[e] > v0) { v0 = lg[e]; i0 = e; }
        float v1 = (i0 == 0) ? lg[1] : lg[0];
        int   i1 = (i0 == 0) ? 1 : 0;
#pragma unroll
        for (int e = 0; e < NE; ++e)
            if (e != i0 && lg[e] > v1) { v1 = lg[e]; i1 = e; }

        float s = 0.f;
#pragma unroll
        for (int e = 0; e < NE; ++e) s += __expf(lg[e] - v0);
        const float g0 = 1.0f / s;
        const float g1 = __expf(v1 - v0) / s;
        const float denom = fmaxf(g0 + g1, EPS_F32);

        const int t_global = tblock + tl;
        const int sel = kk ? i1 : i0;
        out[(size_t)t_global * 16 + kk * 8 + ee] = (ee == sel) ? 1.0f : 0.0f;

        if ((tid & 15) < 2) {
            const float g = (ee == 0) ? (g0 / denom) : (g1 / denom);
            out[(size_t)tokens * 16 + (size_t)t_global * 2 + ee] = g;
        }
    }
}

extern "C" void kernel_launch(void* const* d_in, const int* in_sizes, int n_in,
                              void* d_out, int out_size, void* d_ws, size_t ws_size,
                              hipStream_t stream) {
    const float* x      = (const float*)d_in[0];
    const float* prompt = (const float*)d_in[1];
    const float* W      = (const float*)d_in[2];
    const float* b      = (const float*)d_in[3];
    float* out          = (float*)d_out;

    const int tokens = in_sizes[0] / 4096;   // 8192
    const int grid   = tokens / 8;           // 1024 blocks

    hipLaunchKernelGGL(topk_gate, dim3(grid), dim3(256), 0, stream,
                       x, prompt, W, b, out, tokens);
}

// Round 3
// 226.560 us; speedup vs baseline: 1.0811x; 1.0811x over previous
//
#include <hip/hip_runtime.h>
#include <math.h>

#define NE 8
#define KDIM 4096
#define PDIM 64
#define WROWS (KDIM + PDIM)   // 4160
#define EPS_F32 1.1920929e-07f

// --- tiny setup kernel: W[4160][8] -> Wt[8][4160] in d_ws ---
__global__ __launch_bounds__(256)
void transpose_w(const float* __restrict__ W, float* __restrict__ Wt) {
    const int k = blockIdx.x * 256 + threadIdx.x;
    if (k < WROWS) {
        float v[NE];
#pragma unroll
        for (int e = 0; e < NE; ++e) v[e] = W[(size_t)k * NE + e];
#pragma unroll
        for (int e = 0; e < NE; ++e) Wt[(size_t)e * WROWS + k] = v[e];
    }
}

// Block = 256 threads = 4 waves, handles 4 tokens.
// wave ks = K-quarter: ks covers model-dim [ks*1024, ks*1024+1024);
// ks==3 also covers the 64 prompt dims. Grid = tokens/4 = 2048 blocks.
// ALL loads fully coalesced (Wt is transposed): no scattered W gathers.
__global__ __launch_bounds__(256, 4)
void topk_gate(const float* __restrict__ x,
               const float* __restrict__ prompt,
               const float* __restrict__ Wt,
               const float* __restrict__ b,
               float* __restrict__ out,
               int tokens)
{
    const int tid  = threadIdx.x;
    const int lane = tid & 63;
    const int ks   = tid >> 6;           // K-quarter 0..3
    const int tblock = blockIdx.x * 4;

    __shared__ float lds[4][4][NE];      // [ks][token][expert]

    float acc[4][NE];
#pragma unroll
    for (int t = 0; t < 4; ++t)
#pragma unroll
        for (int e = 0; e < NE; ++e) acc[t][e] = 0.f;

    const int kofs = ks * 1024;

    // 1024 floats per wave / (64 lanes * 4) = 4 iterations
#pragma unroll 2
    for (int i = 0; i < 4; ++i) {
        const int k = kofs + i * 256 + lane * 4;

        // batch ALL loads first so they stay in flight together
        float4 xv[4];
#pragma unroll
        for (int t = 0; t < 4; ++t)
            xv[t] = *(const float4*)(x + (size_t)(tblock + t) * KDIM + k);

        float4 wv[NE];
#pragma unroll
        for (int e = 0; e < NE; ++e)
            wv[e] = *(const float4*)(Wt + (size_t)e * WROWS + k);

#pragma unroll
        for (int t = 0; t < 4; ++t)
#pragma unroll
            for (int e = 0; e < NE; ++e) {
                acc[t][e] = fmaf(xv[t].x, wv[e].x, acc[t][e]);
                acc[t][e] = fmaf(xv[t].y, wv[e].y, acc[t][e]);
                acc[t][e] = fmaf(xv[t].z, wv[e].z, acc[t][e]);
                acc[t][e] = fmaf(xv[t].w, wv[e].w, acc[t][e]);
            }
    }

    // prompt (64 dims): ks==3 wave, lanes 0..15, contiguous Wt rows 4096..4159
    if (ks == 3 && lane < 16) {
        const int k = lane * 4;
        float4 pv[4];
#pragma unroll
        for (int t = 0; t < 4; ++t)
            pv[t] = *(const float4*)(prompt + (size_t)(tblock + t) * PDIM + k);
        float4 wv[NE];
#pragma unroll
        for (int e = 0; e < NE; ++e)
            wv[e] = *(const float4*)(Wt + (size_t)e * WROWS + KDIM + k);
#pragma unroll
        for (int t = 0; t < 4; ++t)
#pragma unroll
            for (int e = 0; e < NE; ++e) {
                acc[t][e] = fmaf(pv[t].x, wv[e].x, acc[t][e]);
                acc[t][e] = fmaf(pv[t].y, wv[e].y, acc[t][e]);
                acc[t][e] = fmaf(pv[t].z, wv[e].z, acc[t][e]);
                acc[t][e] = fmaf(pv[t].w, wv[e].w, acc[t][e]);
            }
    }

    // intra-wave butterfly: every lane gets this wave's full partials
#pragma unroll
    for (int t = 0; t < 4; ++t)
#pragma unroll
        for (int e = 0; e < NE; ++e) {
            float v = acc[t][e];
#pragma unroll
            for (int off = 32; off >= 1; off >>= 1)
                v += __shfl_xor(v, off, 64);
            acc[t][e] = v;
        }

    if (lane < 32) {
        const int t = lane >> 3;
        const int e = lane & 7;
        lds[ks][t][e] = acc[t][e];
    }
    __syncthreads();

    // ---- epilogue: 64 threads, one mask element each ----
    if (tid < 64) {
        const int tl = tid >> 4;          // block-local token 0..3
        const int kk = (tid >> 3) & 1;
        const int ee = tid & 7;

        float lg[NE];
#pragma unroll
        for (int e = 0; e < NE; ++e)
            lg[e] = lds[0][tl][e] + lds[1][tl][e] + lds[2][tl][e] + lds[3][tl][e] + b[e];

        // top-2, strict > so smallest index wins ties (jax.lax.top_k semantics)
        float v0 = lg[0]; int i0 = 0;
#pragma unroll
        for (int e = 1; e < NE; ++e)
            if (lg[e] > v0) { v0 = lg[e]; i0 = e; }
        float v1 = (i0 == 0) ? lg[1] : lg[0];
        int   i1 = (i0 == 0) ? 1 : 0;
#pragma unroll
        for (int e = 0; e < NE; ++e)
            if (e != i0 && lg[e] > v1) { v1 = lg[e]; i1 = e; }

        float s = 0.f;
#pragma unroll
        for (int e = 0; e < NE; ++e) s += __expf(lg[e] - v0);
        const float g0 = 1.0f / s;
        const float g1 = __expf(v1 - v0) / s;
        const float denom = fmaxf(g0 + g1, EPS_F32);

        const int t_global = tblock + tl;
        const int sel = kk ? i1 : i0;
        out[(size_t)t_global * 16 + kk * 8 + ee] = (ee == sel) ? 1.0f : 0.0f;

        if ((tid & 15) < 2) {
            const float g = (ee == 0) ? (g0 / denom) : (g1 / denom);
            out[(size_t)tokens * 16 + (size_t)t_global * 2 + ee] = g;
        }
    }
}

extern "C" void kernel_launch(void* const* d_in, const int* in_sizes, int n_in,
                              void* d_out, int out_size, void* d_ws, size_t ws_size,
                              hipStream_t stream) {
    const float* x      = (const float*)d_in[0];
    const float* prompt = (const float*)d_in[1];
    const float* W      = (const float*)d_in[2];
    const float* b      = (const float*)d_in[3];
    float* out          = (float*)d_out;
    float* Wt           = (float*)d_ws;          // 8*4160*4 = 133 KB

    const int tokens = in_sizes[0] / KDIM;       // 8192

    hipLaunchKernelGGL(transpose_w, dim3((WROWS + 255) / 256), dim3(256), 0, stream,
                       W, Wt);
    hipLaunchKernelGGL(topk_gate, dim3(tokens / 4), dim3(256), 0, stream,
                       x, prompt, Wt, b, out, tokens);
}

// Round 4
// 209.129 us; speedup vs baseline: 1.1712x; 1.0834x over previous
//
#include <hip/hip_runtime.h>
#include <math.h>

#define NE 8
#define KDIM 4096
#define PDIM 64
#define WROWS (KDIM + PDIM)   // 4160
#define EPS_F32 1.1920929e-07f
#define NCHUNK 16             // 4096 / (64 lanes * 4 floats)
#define DEPTH 3               // prefetch depth-2 => 3 register buffer sets

typedef float f4 __attribute__((ext_vector_type(4)));

// --- tiny setup kernel: W[4160][8] -> Wt[8][4160] in d_ws ---
__global__ __launch_bounds__(256)
void transpose_w(const float* __restrict__ W, float* __restrict__ Wt) {
    const int k = blockIdx.x * 256 + threadIdx.x;
    if (k < WROWS) {
        float v[NE];
#pragma unroll
        for (int e = 0; e < NE; ++e) v[e] = W[(size_t)k * NE + e];
#pragma unroll
        for (int e = 0; e < NE; ++e) Wt[(size_t)e * WROWS + k] = v[e];
    }
}

// One wave per block, 4 tokens per wave, FULL K per wave (no cross-wave
// combine, no __syncthreads). Depth-2 software prefetch: 3 register buffer
// sets of (4 x-loads + 8 Wt-loads) = ~24 KB in flight per wave continuously.
// Grid = tokens/4 = 2048 blocks -> 8 waves/CU, all resident from t=0.
__global__ __launch_bounds__(64, 2)
void topk_gate(const float* __restrict__ x,
               const float* __restrict__ prompt,
               const float* __restrict__ Wt,
               const float* __restrict__ b,
               float* __restrict__ out,
               int tokens)
{
    const int lane  = threadIdx.x;      // 0..63
    const int tbase = blockIdx.x * 4;
    const int klane = lane * 4;

    float acc[4][NE];
#pragma unroll
    for (int t = 0; t < 4; ++t)
#pragma unroll
        for (int e = 0; e < NE; ++e) acc[t][e] = 0.f;

    f4 xb[DEPTH][4];
    f4 wb[DEPTH][NE];

    auto load_chunk = [&](int c, int s) {
        const int k = c * 256 + klane;
#pragma unroll
        for (int t = 0; t < 4; ++t)
            xb[s][t] = __builtin_nontemporal_load(
                (const f4*)(x + (size_t)(tbase + t) * KDIM + k));
#pragma unroll
        for (int e = 0; e < NE; ++e)
            wb[s][e] = *(const f4*)(Wt + (size_t)e * WROWS + k);
    };

    load_chunk(0, 0);
    load_chunk(1, 1);

#pragma unroll
    for (int c = 0; c < NCHUNK; ++c) {
        if (c + 2 < NCHUNK) load_chunk(c + 2, (c + 2) % DEPTH);
        const int s = c % DEPTH;
#pragma unroll
        for (int t = 0; t < 4; ++t)
#pragma unroll
            for (int e = 0; e < NE; ++e) {
                acc[t][e] = fmaf(xb[s][t].x, wb[s][e].x, acc[t][e]);
                acc[t][e] = fmaf(xb[s][t].y, wb[s][e].y, acc[t][e]);
                acc[t][e] = fmaf(xb[s][t].z, wb[s][e].z, acc[t][e]);
                acc[t][e] = fmaf(xb[s][t].w, wb[s][e].w, acc[t][e]);
            }
    }

    // prompt part (64 dims): lanes 0..15, contiguous Wt rows 4096..4159
    if (lane < 16) {
        const int k = lane * 4;
        f4 pv[4];
#pragma unroll
        for (int t = 0; t < 4; ++t)
            pv[t] = *(const f4*)(prompt + (size_t)(tbase + t) * PDIM + k);
        f4 wv[NE];
#pragma unroll
        for (int e = 0; e < NE; ++e)
            wv[e] = *(const f4*)(Wt + (size_t)e * WROWS + KDIM + k);
#pragma unroll
        for (int t = 0; t < 4; ++t)
#pragma unroll
            for (int e = 0; e < NE; ++e) {
                acc[t][e] = fmaf(pv[t].x, wv[e].x, acc[t][e]);
                acc[t][e] = fmaf(pv[t].y, wv[e].y, acc[t][e]);
                acc[t][e] = fmaf(pv[t].z, wv[e].z, acc[t][e]);
                acc[t][e] = fmaf(pv[t].w, wv[e].w, acc[t][e]);
            }
    }

    // butterfly reduce: every lane ends with full logits for all 4 tokens
#pragma unroll
    for (int t = 0; t < 4; ++t)
#pragma unroll
        for (int e = 0; e < NE; ++e) {
            float v = acc[t][e];
#pragma unroll
            for (int off = 32; off >= 1; off >>= 1)
                v += __shfl_xor(v, off, 64);
            acc[t][e] = v;
        }

    // ---- epilogue: lane = tt*16 + kk*8 + ee -> one mask element per lane ----
    const int tt = lane >> 4;
    const int kk = (lane >> 3) & 1;
    const int ee = lane & 7;

    float lg[NE];
#pragma unroll
    for (int e = 0; e < NE; ++e) {
        float v = acc[0][e];
        if (tt == 1) v = acc[1][e];
        if (tt == 2) v = acc[2][e];
        if (tt == 3) v = acc[3][e];
        lg[e] = v + b[e];
    }

    // top-2, strict > so smallest index wins ties (jax.lax.top_k semantics)
    float v0 = lg[0]; int i0 = 0;
#pragma unroll
    for (int e = 1; e < NE; ++e)
        if (lg[e] > v0) { v0 = lg[e]; i0 = e; }
    float v1 = (i0 == 0) ? lg[1] : lg[0];
    int   i1 = (i0 == 0) ? 1 : 0;
#pragma unroll
    for (int e = 0; e < NE; ++e)
        if (e != i0 && lg[e] > v1) { v1 = lg[e]; i1 = e; }

    float s = 0.f;
#pragma unroll
    for (int e = 0; e < NE; ++e) s += __expf(lg[e] - v0);
    const float g0 = 1.0f / s;
    const float g1 = __expf(v1 - v0) / s;
    const float denom = fmaxf(g0 + g1, EPS_F32);

    const int sel = kk ? i1 : i0;
    const int t_global = tbase + tt;
    out[(size_t)t_global * 16 + kk * 8 + ee] = (ee == sel) ? 1.0f : 0.0f;

    if ((lane & 15) < 2) {
        const float g = (ee == 0) ? (g0 / denom) : (g1 / denom);
        out[(size_t)tokens * 16 + (size_t)t_global * 2 + ee] = g;
    }
}

extern "C" void kernel_launch(void* const* d_in, const int* in_sizes, int n_in,
                              void* d_out, int out_size, void* d_ws, size_t ws_size,
                              hipStream_t stream) {
    const float* x      = (const float*)d_in[0];
    const float* prompt = (const float*)d_in[1];
    const float* W      = (const float*)d_in[2];
    const float* b      = (const float*)d_in[3];
    float* out          = (float*)d_out;
    float* Wt           = (float*)d_ws;          // 8*4160*4 = 133 KB

    const int tokens = in_sizes[0] / KDIM;       // 8192

    hipLaunchKernelGGL(transpose_w, dim3((WROWS + 255) / 256), dim3(256), 0, stream,
                       W, Wt);
    hipLaunchKernelGGL(topk_gate, dim3(tokens / 4), dim3(64), 0, stream,
                       x, prompt, Wt, b, out, tokens);
}